// Round 17
// baseline (391.563 us; speedup 1.0000x reference)
//
#include <hip/hip_runtime.h>
#include <hip/hip_bf16.h>

// out[B,S,O] = A[B,S,I] @ W[O,I]^T * scales[O] + bias[O]
// M = 16384, N = 4096, K = 4096. Output fp32.
// i8 path: A per-row quant (amax/127), W exact i8; mfma_i32_16x16x64_i8;
// dequant epilogue acc * (ascale[m]*scales[n]) + bias[n].
// R17 vs R16: BK 128->64 (parameter rescale of the twice-proven R7 skeleton).
// LDS halves to 64 KiB -> 2 blocks/CU; independent blocks' phases drift, so
// one block's MFMA fills the other's read/barrier stall (m114 overlap).
// Same 8-barrier read->BAR->consume semantics; ledger/swizzle re-derived for
// 64B rows (1 gload_lds per half-tile per wave; VM(3) fence).
#define M_TOTAL 16384
#define N_TOTAL 4096
#define K_TOTAL 4096
#define NT (K_TOTAL / 64)  // 64 K-tiles of BK=64 (i8)
#define W_BLOCKS 2048

typedef __attribute__((ext_vector_type(4))) int i32x4;

__device__ __forceinline__ unsigned pack4(int a, int b, int c, int d) {
  return (a & 0xFF) | ((b & 0xFF) << 8) | ((c & 0xFF) << 16) | ((d & 0xFF) << 24);
}

// ---- fused conversions: blocks [0,W_BLOCKS) pack W, rest quantize A rows ----
__global__ __launch_bounds__(256) void cvt_fused(
    const float* __restrict__ A, unsigned* __restrict__ Aq,
    float* __restrict__ ascale, const int* __restrict__ W,
    unsigned* __restrict__ Wq) {
  const int tid = threadIdx.x;
  if (blockIdx.x < W_BLOCKS) {
    const int n4 = (N_TOTAL * K_TOTAL) / 4;
    const int stride = W_BLOCKS * 256;
    for (int i = blockIdx.x * 256 + tid; i < n4; i += stride) {
      int4 v = reinterpret_cast<const int4*>(W)[i];
      Wq[i] = pack4(v.x, v.y, v.z, v.w);
    }
    return;
  }
  const int row = blockIdx.x - W_BLOCKS;
  const float4* src = reinterpret_cast<const float4*>(A + (size_t)row * K_TOTAL);
  float4 v[4];
#pragma unroll
  for (int c = 0; c < 4; ++c) v[c] = src[tid + 256 * c];
  float amax = 0.0f;
#pragma unroll
  for (int c = 0; c < 4; ++c)
    amax = fmaxf(amax, fmaxf(fmaxf(fabsf(v[c].x), fabsf(v[c].y)),
                             fmaxf(fabsf(v[c].z), fabsf(v[c].w))));
#pragma unroll
  for (int off = 32; off > 0; off >>= 1) amax = fmaxf(amax, __shfl_xor(amax, off, 64));
  __shared__ float wmax[4];
  if ((tid & 63) == 0) wmax[tid >> 6] = amax;
  __syncthreads();
  amax = fmaxf(fmaxf(wmax[0], wmax[1]), fmaxf(wmax[2], wmax[3]));
  amax = fmaxf(amax, 1e-20f);
  const float rs = 127.0f / amax;
  if (tid == 0) ascale[row] = amax * (1.0f / 127.0f);

  unsigned* dst = Aq + (size_t)row * (K_TOTAL / 4);
#pragma unroll
  for (int c = 0; c < 4; ++c) {
    int q[4];
    float f[4] = {v[c].x, v[c].y, v[c].z, v[c].w};
#pragma unroll
    for (int i = 0; i < 4; ++i) {
      int t = (int)rintf(f[i] * rs);
      q[i] = t < -127 ? -127 : (t > 127 ? 127 : t);
    }
    dst[tid + 256 * c] = pack4(q[0], q[1], q[2], q[3]);
  }
}

// ======== 256x256 i8 GEMM — R7 skeleton rescaled to BK=64 (R17) ========
#define GLOAD_LDS16(gp, lp)                                                \
  __builtin_amdgcn_global_load_lds(                                        \
      (const __attribute__((address_space(1))) void*)(gp),                 \
      (__attribute__((address_space(3))) void*)(lp), 16, 0, 0)

#define BAR() asm volatile("s_barrier" ::: "memory")
#define VM(n) asm volatile("s_waitcnt vmcnt(" #n ")" ::: "memory")

// LDS map (65536 B): buf b at b*32768: A_h0 [0,8K) A_h1 [8K,16K)
// B_h0 [16K,24K) B_h1 [24K,32K). Half-tile = 128 rows x 64 i8, row = 64 B.
// Swizzle: 16B block c16 of row r stored at c16 ^ ((r>>1)&3). Fragment reads
// hit each bank exactly 2x per 16-lane group (2-way = free, m136).
// gload_lds writes linearly (wave w: rows w*16+(l>>2), block l&3), so the
// GLOBAL source col-block is inverse-swizzled: (l&3) ^ ((l>>3)&3) (rule #21;
// ((w*16+(l>>2))>>1)&3 == (l>>3)&3 because w*8 mod 4 == 0).
// Ledger (1 load/STAGE): invariant at P1 head: outstanding oldest-first
// {Bh0(t+1),Bh1(t+1),Ah0(t+1)} = 3, tile t landed. P1 +Ah1(t+1)=4,
// P2 +Bh0(t+2)=5, P3 +Bh1(t+2)=6, P4 +Ah0(t+2)=7 -> VM(3)@P4-end drains
// 4 oldest = tile t+1 exactly. Prologue: 7 loads -> VM(3) drains tile0.
// Fences precede barriers; reads sit in their consuming phase (race-free,
// inherited from R7's twice-proven structure).

__global__ __launch_bounds__(512, 2) void w8a16_gemm_i8(
    const signed char* __restrict__ A,   // [M][K] i8
    const signed char* __restrict__ Bt,  // [N][K] i8
    const float* __restrict__ ascale,    // [M]
    const float* __restrict__ scales, const float* __restrict__ bias,
    float* __restrict__ C) {
  __shared__ alignas(16) unsigned char lds[65536];

  const int tid = threadIdx.x;
  const int w = tid >> 6, l = tid & 63;
  const int wr = w >> 2, wc = w & 3;  // 2x4 wave grid; per-wave 128x64 output
  const int bn = blockIdx.x, bm = blockIdx.y;

  // staging address (pre-inverse-swizzled source)
  const int rowq = tid >> 2;                         // w*16 + (l>>2), 0..127
  const int colb = (((l & 3) ^ ((l >> 3) & 3)) << 4);  // col byte block
  const signed char* pA = A + (size_t)(bm * 256 + rowq) * K_TOTAL + colb;
  const signed char* pB = Bt + (size_t)(bn * 256 + rowq) * K_TOTAL + colb;
  unsigned char* const ldsp = lds;
  const int woff = w << 10;

#define SDA(b_, h_) (ldsp + (b_) * 32768 + (h_) * 8192 + woff)
#define SDB(b_, h_) (ldsp + (b_) * 32768 + 16384 + (h_) * 8192 + woff)
#define STAGE_A(b_, h_, t_)                                                    \
  GLOAD_LDS16(pA + (size_t)((h_) * 128) * K_TOTAL + (t_) * 64, SDA(b_, h_))
#define STAGE_B(b_, h_, t_)                                                    \
  GLOAD_LDS16(pB + (size_t)((h_) * 128) * K_TOTAL + (t_) * 64, SDB(b_, h_))

  // fragment read: row (l&15) within frag, k-block (l>>4), swizzle (l>>1)&3
  const int arow = ((l & 15) << 6) + ((((l >> 4) ^ (l >> 1)) & 3) << 4);

  i32x4 af[4];   // current m-half: 4 m-frags (16 i8 each = full K=64 slice)
  i32x4 bfr[4];  // whole-tile B: 4 n-frags
  i32x4 acc[8][4] = {{}};

#define RD_A(mh_)                                                             \
  do {                                                                        \
    const unsigned char* Ab_ = ldsp + bsel * 32768 + wr * 8192;               \
    _Pragma("unroll") for (int fm = 0; fm < 4; ++fm)                          \
        af[fm] = *(const i32x4*)(Ab_ + ((mh_) * 4 + fm) * 1024 + arow);       \
  } while (0)
#define RD_B(nh_)                                                             \
  do {                                                                        \
    const unsigned char* Bb_ = ldsp + bsel * 32768 + 16384 +                  \
                               (wc >> 1) * 8192 + (wc & 1) * 4096;            \
    _Pragma("unroll") for (int fn = 0; fn < 2; ++fn)                          \
        bfr[(nh_) * 2 + fn] =                                                 \
            *(const i32x4*)(Bb_ + ((nh_) * 2 + fn) * 1024 + arow);            \
  } while (0)
#define QUAD(mh_, nh_)                                                        \
  do {                                                                        \
    __builtin_amdgcn_s_setprio(1);                                            \
    _Pragma("unroll") for (int m = 0; m < 4; ++m)                             \
        _Pragma("unroll") for (int n = 0; n < 2; ++n)                         \
            acc[(mh_) * 4 + m][(nh_) * 2 + n] =                               \
                __builtin_amdgcn_mfma_i32_16x16x64_i8(                        \
                    af[m], bfr[(nh_) * 2 + n],                                \
                    acc[(mh_) * 4 + m][(nh_) * 2 + n], 0, 0, 0);              \
    __builtin_amdgcn_s_setprio(0);                                            \
  } while (0)

  // --- prologue: tile0 + B(1)h0,h1 + A(1)h0 = 7 loads; VM(3) drains tile0 ---
  STAGE_A(0, 0, 0); STAGE_A(0, 1, 0);
  STAGE_B(0, 0, 0); STAGE_B(0, 1, 0);
  STAGE_B(1, 0, 1); STAGE_B(1, 1, 1);
  STAGE_A(1, 0, 1);
  VM(3);
  BAR();

  // --- main loop (R7 structure): 4 phases/tile, reads in consuming phase ---
  for (int t = 0; t < NT; ++t) {
    const int bsel = t & 1;
    // P1
    RD_A(0); RD_B(0);
    if (t + 1 < NT) STAGE_A(bsel ^ 1, 1, t + 1);
    BAR();
    QUAD(0, 0);
    BAR();
    // P2
    RD_B(1);
    if (t + 2 < NT) STAGE_B(bsel, 0, t + 2);
    BAR();
    QUAD(0, 1);
    BAR();
    // P3
    RD_A(1);
    if (t + 2 < NT) STAGE_B(bsel, 1, t + 2);
    BAR();
    QUAD(1, 1);
    BAR();
    // P4 (B-frags reused from registers)
    if (t + 2 < NT) STAGE_A(bsel, 0, t + 2);
    BAR();
    QUAD(1, 0);
    if (t < NT - 2) { VM(3); } else { VM(0); }
    BAR();
  }

  // --- epilogue: C/D col=lane&15, row=(lane>>4)*4+reg (dtype-independent);
  //     dequant acc * (ascale[row]*scales[col]) + bias ---
  const int row0 = bm * 256 + wr * 128 + ((l >> 4) << 2);
  const int col0 = bn * 256 + wc * 64 + (l & 15);
#pragma unroll
  for (int fn = 0; fn < 4; ++fn) {
    const int col = col0 + fn * 16;
    const float sc = scales[col];
    const float bi = bias[col];
#pragma unroll
    for (int fm = 0; fm < 8; ++fm) {
      const int r = row0 + fm * 16;
      float* cp = C + (size_t)r * N_TOTAL + col;
#pragma unroll
      for (int j = 0; j < 4; ++j)
        cp[(size_t)j * N_TOTAL] = fmaf((float)acc[fm][fn][j], ascale[r + j] * sc, bi);
    }
  }
}

// ---- guarded fallback (only if d_ws too small) ----
__global__ void naive_gemm(const float* __restrict__ A, const int* __restrict__ W,
                           const float* __restrict__ scales, const float* __restrict__ bias,
                           float* __restrict__ C) {
  size_t idx = (size_t)blockIdx.x * blockDim.x + threadIdx.x;
  if (idx >= (size_t)M_TOTAL * N_TOTAL) return;
  const int n = (int)(idx % N_TOTAL);
  const size_t m = idx / N_TOTAL;
  const float* a = A + m * (size_t)K_TOTAL;
  const int* w = W + (size_t)n * K_TOTAL;
  float s = 0.f;
  for (int k = 0; k < K_TOTAL; ++k) s = fmaf(a[k], (float)w[k], s);
  C[idx] = fmaf(s, scales[n], bias[n]);
}

extern "C" void kernel_launch(void* const* d_in, const int* in_sizes, int n_in,
                              void* d_out, int out_size, void* d_ws, size_t ws_size,
                              hipStream_t stream) {
  const float* A = (const float*)d_in[0];
  const int* W = (const int*)d_in[1];
  const float* scales = (const float*)d_in[2];
  const float* bias = (const float*)d_in[3];
  float* out = (float*)d_out;

  const size_t a_elems = (size_t)M_TOTAL * K_TOTAL;
  const size_t w_elems = (size_t)N_TOTAL * K_TOTAL;
  const size_t need = a_elems + w_elems + (size_t)M_TOTAL * sizeof(float);

  if (ws_size >= need) {
    signed char* A_q = (signed char*)d_ws;
    signed char* W_q = A_q + a_elems;
    float* a_s = (float*)(W_q + w_elems);
    cvt_fused<<<W_BLOCKS + M_TOTAL, 256, 0, stream>>>(A, (unsigned*)A_q, a_s, W,
                                                      (unsigned*)W_q);
    dim3 grid(N_TOTAL / 256, M_TOTAL / 256);  // (16, 64)
    w8a16_gemm_i8<<<grid, 512, 0, stream>>>(A_q, W_q, a_s, scales, bias, out);
  } else {
    size_t total = (size_t)M_TOTAL * N_TOTAL;
    naive_gemm<<<(unsigned)((total + 255) / 256), 256, 0, stream>>>(A, W, scales, bias, out);
  }
}